// Round 18
// baseline (204.989 us; speedup 1.0000x reference)
//
#include <hip/hip_runtime.h>
#include <cstdint>
#include <cstddef>

#define NN 100000
#define D 128
#define K2 256        // GEMM K: [h | neigh]
#define BM 32         // rows per block; grid = NN/BM = 3125 exactly

typedef __attribute__((ext_vector_type(8))) short bf16x8;
typedef __attribute__((ext_vector_type(4))) float f32x4;

__device__ inline float bfhi2f(unsigned int u) {
    union { unsigned int i; float f; } v; v.i = u & 0xffff0000u; return v.f;
}
__device__ inline float bflo2f(unsigned int u) {
    union { unsigned int i; float f; } v; v.i = u << 16; return v.f;
}
__device__ inline unsigned short f2bf(float f) {  // RNE
    union { float f; unsigned int i; } v; v.f = f;
    unsigned int r = v.i + 0x7FFFu + ((v.i >> 16) & 1u);
    return (unsigned short)(r >> 16);
}

// ---------------- degree ----------------
__global__ void k_deg(const int* __restrict__ dst, int ne, int* __restrict__ deg) {
    int e = blockIdx.x * blockDim.x + threadIdx.x;
    if (e < ne) atomicAdd(&deg[dst[e]], 1);
}

// ---------------- scan: per-chunk reduce ----------------
__global__ void k_chunk_reduce(const int* __restrict__ deg, int n, int* __restrict__ bsum) {
    __shared__ int s[256];
    int i = blockIdx.x * 256 + threadIdx.x;
    s[threadIdx.x] = (i < n) ? deg[i] : 0;
    __syncthreads();
    for (int off = 128; off > 0; off >>= 1) {
        if (threadIdx.x < off) s[threadIdx.x] += s[threadIdx.x + off];
        __syncthreads();
    }
    if (threadIdx.x == 0) bsum[blockIdx.x] = s[0];
}

// ---------------- scan of partials: one block (nb <= 512) ----------------
__global__ __launch_bounds__(512) void k_scan_partials(int* __restrict__ bsum, int nb,
                                                       int* __restrict__ rowptr, int n) {
    __shared__ int s[512];
    int tid = threadIdx.x;
    int v = (tid < nb) ? bsum[tid] : 0;
    s[tid] = v;
    __syncthreads();
    for (int off = 1; off < 512; off <<= 1) {
        int t = (tid >= off) ? s[tid - off] : 0;
        __syncthreads();
        s[tid] += t;
        __syncthreads();
    }
    if (tid < nb) bsum[tid] = s[tid] - v;
    if (tid == nb - 1) rowptr[n] = s[tid];
}

// ---------------- per-chunk exclusive scan + invdeg + cursor init ----------------
__global__ void k_chunk_scan(const int* __restrict__ deg, int n, const int* __restrict__ bsum,
                             int* __restrict__ rowptr, int* __restrict__ cursor,
                             float* __restrict__ invd) {
    __shared__ int s[256];
    int tid = threadIdx.x;
    int i = blockIdx.x * 256 + tid;
    int v = (i < n) ? deg[i] : 0;
    s[tid] = v;
    __syncthreads();
    for (int off = 1; off < 256; off <<= 1) {
        int t = (tid >= off) ? s[tid - off] : 0;
        __syncthreads();
        s[tid] += t;
        __syncthreads();
    }
    if (i < n) {
        int excl = bsum[blockIdx.x] + s[tid] - v;
        rowptr[i] = excl;
        cursor[i] = excl;  // k_fill bumps this directly
        invd[i] = 1.0f / fmaxf((float)v, 1.0f);
    }
}

// ---------------- CSR fill (cursor pre-seeded with rowptr) ----------------
__global__ void k_fill(const int* __restrict__ src, const int* __restrict__ dst, int ne,
                       int* __restrict__ cursor, int* __restrict__ col) {
    int e = blockIdx.x * blockDim.x + threadIdx.x;
    if (e < ne) {
        int p = atomicAdd(&cursor[dst[e]], 1);
        col[p] = src[e];
    }
}

// ---------------- prep: h -> HtA bf16, weights -> Btf frag-order, zero deg ----------------
#define T_H   (NN * 32)          // 3,200,000
#define T_BT  (3 * 128 * K2)     // 98,304
#define T_Z   (NN / 4)           // 25,000 int4 stores
__global__ void k_prep(const float* __restrict__ h, const float* __restrict__ Ws,
                       const float* __restrict__ Wn, unsigned short* __restrict__ Ht,
                       unsigned short* __restrict__ Btf, int4* __restrict__ degz) {
    int t = blockIdx.x * 256 + threadIdx.x;
    if (t < T_H) {
        int row = t >> 5, c4 = (t & 31) << 2;
        float4 v = *(const float4*)(h + (size_t)row * D + c4);
        ushort4 o = make_ushort4(f2bf(v.x), f2bf(v.y), f2bf(v.z), f2bf(v.w));
        *(ushort4*)(Ht + (size_t)row * D + c4) = o;
    } else if (t < T_H + T_BT) {
        int t2 = t - T_H;
        int j = t2 & 7; int rest = t2 >> 3;
        int lane = rest & 63; rest >>= 6;
        int ks = rest & 7; rest >>= 3;
        int nf = rest & 7; int l = rest >> 3;
        int nn = nf * 16 + (lane & 15);
        int k = ks * 32 + (lane >> 4) * 8 + j;
        float v = (k < D) ? Ws[(size_t)l * D * D + (size_t)k * D + nn]
                          : Wn[(size_t)l * D * D + (size_t)(k - D) * D + nn];
        Btf[t2] = f2bf(v);
    } else {
        int t3 = t - T_H - T_BT;
        if (t3 < T_Z) degz[t3] = make_int4(0, 0, 0, 0);
    }
}

// ---------------- fused layer, BM=32: gather 32 nodes -> LDS neigh half, h half via
// global_load_lds, MFMA GEMM, LDS-transposed coalesced epilogue.
// Gather v2: group g processes nodes rowA=wid*8+g AND rowB=rowA+4 concurrently ->
// 16 independent dwordx4 row-loads in flight per wave (2x MLP vs round 17).
__global__ __launch_bounds__(256, 4) void k_layer(const unsigned short* __restrict__ Hin,
                                                  const unsigned short* __restrict__ Btf,
                                                  const float* __restrict__ bias,
                                                  const int* __restrict__ rowptr,
                                                  const int* __restrict__ col,
                                                  const float* __restrict__ invd,
                                                  unsigned short* __restrict__ Hout,
                                                  float* __restrict__ outf,
                                                  int relu) {
    __shared__ unsigned short smem[BM * 256];          // 16 KB total
    unsigned short* Ah = smem;                          // 8 KB: h half (256B rows, swizzled)
    unsigned short* An = smem + BM * 128;               // 8 KB: neigh half
    int tid = threadIdx.x;
    int wid = tid >> 6;
    int lane = tid & 63;
    int g = lane >> 4;
    int lane16 = lane & 15;
    int m0 = blockIdx.x * BM;

    // 1) issue h-half staging first: HBM latency hides under the gather.
#pragma unroll
    for (int i = 0; i < 2; ++i) {
        int chunk = wid * 2 + i;
        int o = chunk * 1024 + lane * 16;
        int row = o >> 8;
        int cb = o & 255;
        int scb = cb ^ ((row & 7) << 4);
        const unsigned short* gsrc = Hin + (size_t)(m0 + row) * D + (scb >> 1);
        __builtin_amdgcn_global_load_lds(
            (const __attribute__((address_space(1))) unsigned int*)gsrc,
            (__attribute__((address_space(3))) unsigned int*)((char*)Ah + chunk * 1024),
            16, 0, 0);
    }

    // 2) gather: two nodes per group processed concurrently (16 loads in flight/wave)
    int coff = lane16 * 8;  // 8 channels (16B) per lane
    {
        int rowA = wid * 8 + g;
        int rowB = rowA + 4;
        int nodeA = m0 + rowA, nodeB = m0 + rowB;   // < NN always (NN = 3125*32)
        int e0A = rowptr[nodeA];
        int nA = rowptr[nodeA + 1] - e0A;
        int e0B = rowptr[nodeB];
        int nB = rowptr[nodeB + 1] - e0B;
        float invA = invd[nodeA], invB = invd[nodeB];
        float aA0 = 0.f, aA1 = 0.f, aA2 = 0.f, aA3 = 0.f, aA4 = 0.f, aA5 = 0.f, aA6 = 0.f, aA7 = 0.f;
        float aB0 = 0.f, aB1 = 0.f, aB2 = 0.f, aB3 = 0.f, aB4 = 0.f, aB5 = 0.f, aB6 = 0.f, aB7 = 0.f;
        int nmax = nA > nB ? nA : nB;
        for (int base = 0; base < nmax; base += 16) {
            int remA = nA - base, remB = nB - base;       // group-uniform
            int cvA = 0, cvB = 0;
            if (remA > 0) cvA = col[e0A + base + (lane16 < remA ? lane16 : remA - 1)];
            if (remB > 0) cvB = col[e0B + base + (lane16 < remB ? lane16 : remB - 1)];
            int limA = remA < 16 ? remA : 16;
            int limB = remB < 16 ? remB : 16;
#pragma unroll
            for (int j = 0; j < 16; j += 8) {
                uint4 uA[8], uB[8];
                bool doA = remA > j, doB = remB > j;      // group-uniform batch guards
                if (doA) {
#pragma unroll
                    for (int k = 0; k < 8; ++k) {
                        int ee = j + k;
                        int eidx = ee < limA ? ee : limA - 1;  // clamp: dup loads cache-hot
                        int si = __shfl(cvA, (g << 4) + eidx, 64);
                        uA[k] = *(const uint4*)(Hin + (size_t)si * D + coff);
                    }
                }
                if (doB) {
#pragma unroll
                    for (int k = 0; k < 8; ++k) {
                        int ee = j + k;
                        int eidx = ee < limB ? ee : limB - 1;
                        int si = __shfl(cvB, (g << 4) + eidx, 64);
                        uB[k] = *(const uint4*)(Hin + (size_t)si * D + coff);
                    }
                }
                if (doA) {
#pragma unroll
                    for (int k = 0; k < 8; ++k) {
                        bool live = (j + k) < limA;
                        unsigned int ux = live ? uA[k].x : 0u, uy = live ? uA[k].y : 0u;
                        unsigned int uz = live ? uA[k].z : 0u, uw = live ? uA[k].w : 0u;
                        aA0 += bflo2f(ux); aA1 += bfhi2f(ux);
                        aA2 += bflo2f(uy); aA3 += bfhi2f(uy);
                        aA4 += bflo2f(uz); aA5 += bfhi2f(uz);
                        aA6 += bflo2f(uw); aA7 += bfhi2f(uw);
                    }
                }
                if (doB) {
#pragma unroll
                    for (int k = 0; k < 8; ++k) {
                        bool live = (j + k) < limB;
                        unsigned int ux = live ? uB[k].x : 0u, uy = live ? uB[k].y : 0u;
                        unsigned int uz = live ? uB[k].z : 0u, uw = live ? uB[k].w : 0u;
                        aB0 += bflo2f(ux); aB1 += bfhi2f(ux);
                        aB2 += bflo2f(uy); aB3 += bfhi2f(uy);
                        aB4 += bflo2f(uz); aB5 += bfhi2f(uz);
                        aB6 += bflo2f(uw); aB7 += bfhi2f(uw);
                    }
                }
            }
        }
        uint4 oA;
        oA.x = ((unsigned int)f2bf(aA1 * invA) << 16) | f2bf(aA0 * invA);
        oA.y = ((unsigned int)f2bf(aA3 * invA) << 16) | f2bf(aA2 * invA);
        oA.z = ((unsigned int)f2bf(aA5 * invA) << 16) | f2bf(aA4 * invA);
        oA.w = ((unsigned int)f2bf(aA7 * invA) << 16) | f2bf(aA6 * invA);
        *(uint4*)((char*)An + rowA * 256 + ((lane16 * 16) ^ ((rowA & 7) << 4))) = oA;
        uint4 oB;
        oB.x = ((unsigned int)f2bf(aB1 * invB) << 16) | f2bf(aB0 * invB);
        oB.y = ((unsigned int)f2bf(aB3 * invB) << 16) | f2bf(aB2 * invB);
        oB.z = ((unsigned int)f2bf(aB5 * invB) << 16) | f2bf(aB4 * invB);
        oB.w = ((unsigned int)f2bf(aB7 * invB) << 16) | f2bf(aB6 * invB);
        *(uint4*)((char*)An + rowB * 256 + ((lane16 * 16) ^ ((rowB & 7) << 4))) = oB;
    }

    // 3) B fragments (after gather: keeps gather-phase register pressure low)
    bf16x8 bfr[2][8];
#pragma unroll
    for (int q = 0; q < 2; ++q) {
        int nf = wid + q * 4;
#pragma unroll
        for (int ks = 0; ks < 8; ++ks)
            bfr[q][ks] = *(const bf16x8*)(Btf + (size_t)(((nf * 8 + ks) << 6) + lane) * 8);
    }

    __syncthreads();  // drains global_load_lds + orders ds_writes

    // 4) MFMA: K = 256 = [h: ks 0..3 from Ah | neigh: ks 4..7 from An]
    f32x4 acc[2][2];
#pragma unroll
    for (int mt = 0; mt < 2; ++mt)
#pragma unroll
        for (int q = 0; q < 2; ++q) acc[mt][q] = (f32x4){0.f, 0.f, 0.f, 0.f};

#pragma unroll
    for (int mt = 0; mt < 2; ++mt) {
        int row = mt * 16 + lane16;
        int swz = (row & 7) << 4;
        bf16x8 a[8];
#pragma unroll
        for (int ks = 0; ks < 8; ++ks) {
            int kb = ks * 64 + g * 16;  // byte col in [0,512)
            const char* basep = (kb < 256) ? (const char*)Ah : (const char*)An;
            int cb2 = (kb & 255) ^ swz;
            a[ks] = *(const bf16x8*)(basep + row * 256 + cb2);
        }
#pragma unroll
        for (int ks = 0; ks < 8; ++ks) {
            acc[mt][0] = __builtin_amdgcn_mfma_f32_16x16x32_bf16(a[ks], bfr[0][ks], acc[mt][0], 0, 0, 0);
            acc[mt][1] = __builtin_amdgcn_mfma_f32_16x16x32_bf16(a[ks], bfr[1][ks], acc[mt][1], 0, 0, 0);
        }
    }

    // 5) epilogue: bias+relu -> LDS (swizzled) -> coalesced stores.
    float bv[2];
    bv[0] = bias[wid * 16 + lane16];
    bv[1] = bias[(wid + 4) * 16 + lane16];
    __syncthreads();  // all ds_reads done; smem reusable

    if (outf) {
        // fp32: 32 rows x 512B = 16KB (whole smem)
#pragma unroll
        for (int mt = 0; mt < 2; ++mt) {
#pragma unroll
            for (int q = 0; q < 2; ++q) {
#pragma unroll
                for (int i = 0; i < 4; ++i) {
                    int row = mt * 16 + g * 4 + i;
                    int fe = ((row & 7) << 4) ^ ((row & 8) << 2);
                    float v = acc[mt][q][i] + bv[q];
                    int colb = ((wid + q * 4) * 16 + lane16) * 4;
                    *(float*)((char*)smem + row * 512 + (colb ^ fe)) = v;
                }
            }
        }
        __syncthreads();
        int row = tid >> 3, seg = tid & 7;
        int fe = ((row & 7) << 4) ^ ((row & 8) << 2);
#pragma unroll
        for (int j = 0; j < 4; ++j) {
            int lb = seg * 64 + j * 16;
            uint4 val = *(const uint4*)((char*)smem + row * 512 + (lb ^ fe));
            *(uint4*)((char*)outf + (size_t)(m0 + row) * 512 + lb) = val;
        }
    } else {
        // bf16: 32 rows x 256B = 8KB
#pragma unroll
        for (int mt = 0; mt < 2; ++mt) {
#pragma unroll
            for (int q = 0; q < 2; ++q) {
#pragma unroll
                for (int i = 0; i < 4; ++i) {
                    int row = mt * 16 + g * 4 + i;
                    int fe = ((row & 7) << 4) ^ ((row & 8) << 2);
                    float v = acc[mt][q][i] + bv[q];
                    if (relu) v = fmaxf(v, 0.f);
                    int colb = ((wid + q * 4) * 16 + lane16) * 2;
                    *(unsigned short*)((char*)smem + row * 256 + (colb ^ fe)) = f2bf(v);
                }
            }
        }
        __syncthreads();
        int row = tid >> 3, seg = tid & 7;
        int fe = ((row & 7) << 4) ^ ((row & 8) << 2);
#pragma unroll
        for (int j = 0; j < 2; ++j) {
            int lb = seg * 32 + j * 16;
            uint4 val = *(const uint4*)((char*)smem + row * 256 + (lb ^ fe));
            *(uint4*)((char*)Hout + (size_t)(m0 + row) * 256 + lb) = val;
        }
    }
}

extern "C" void kernel_launch(void* const* d_in, const int* in_sizes, int n_in,
                              void* d_out, int out_size, void* d_ws, size_t ws_size,
                              hipStream_t stream) {
    const float* h = (const float*)d_in[0];
    const int* src = (const int*)d_in[1];
    const int* dst = (const int*)d_in[2];
    const float* Ws = (const float*)d_in[3];
    const float* Wn = (const float*)d_in[4];
    const float* b = (const float*)d_in[5];
    float* out = (float*)d_out;
    int ne = in_sizes[1];

    // workspace
    char* ws = (char*)d_ws;
    unsigned short* HtA = (unsigned short*)ws; ws += (size_t)NN * D * sizeof(unsigned short);
    unsigned short* HtB = (unsigned short*)ws; ws += (size_t)NN * D * sizeof(unsigned short);
    int* col = (int*)ws;    ws += (size_t)ne * sizeof(int);
    unsigned short* Btf = (unsigned short*)ws; ws += (size_t)3 * 128 * K2 * sizeof(unsigned short);
    int* deg = (int*)ws;    ws += (size_t)NN * sizeof(int);
    int* cursor = (int*)ws; ws += (size_t)NN * sizeof(int);
    int* rowptr = (int*)ws; ws += ((size_t)(NN + 1) * sizeof(int) + 15) / 16 * 16;
    int* bsum = (int*)ws;   ws += 512 * sizeof(int);
    float* invd = (float*)ws;

    int nchunk = (NN + 255) / 256;  // 391
    int nprep = (T_H + T_BT + T_Z + 255) / 256;
    k_prep<<<nprep, 256, 0, stream>>>(h, Ws, Wn, HtA, Btf, (int4*)deg);  // also zeros deg
    k_deg<<<(ne + 255) / 256, 256, 0, stream>>>(dst, ne, deg);
    k_chunk_reduce<<<nchunk, 256, 0, stream>>>(deg, NN, bsum);
    k_scan_partials<<<1, 512, 0, stream>>>(bsum, nchunk, rowptr, NN);
    k_chunk_scan<<<nchunk, 256, 0, stream>>>(deg, NN, bsum, rowptr, cursor, invd);
    k_fill<<<(ne + 255) / 256, 256, 0, stream>>>(src, dst, ne, cursor, col);

    int ngrid = NN / BM;  // 3125 exactly
    // layer 0: HtA -> HtB ; layer 1: HtB -> HtA ; layer 2: HtA -> out (fp32)
    k_layer<<<ngrid, 256, 0, stream>>>(HtA, Btf, b, rowptr, col, invd,
                                       HtB, nullptr, 1);
    k_layer<<<ngrid, 256, 0, stream>>>(HtB, Btf + (size_t)1 * 128 * K2, b + 1 * D,
                                       rowptr, col, invd, HtA, nullptr, 1);
    k_layer<<<ngrid, 256, 0, stream>>>(HtA, Btf + (size_t)2 * 128 * K2, b + 2 * D,
                                       rowptr, col, invd, nullptr, out, 0);
}

// Round 19
// 200.777 us; speedup vs baseline: 1.0210x; 1.0210x over previous
//
#include <hip/hip_runtime.h>
#include <cstdint>
#include <cstddef>

#define NN 100000
#define D 128
#define K2 256        // GEMM K: [h | neigh]
#define BM 32         // rows per block; grid = NN/BM = 3125 exactly

typedef __attribute__((ext_vector_type(8))) short bf16x8;
typedef __attribute__((ext_vector_type(4))) float f32x4;

__device__ inline float bfhi2f(unsigned int u) {
    union { unsigned int i; float f; } v; v.i = u & 0xffff0000u; return v.f;
}
__device__ inline float bflo2f(unsigned int u) {
    union { unsigned int i; float f; } v; v.i = u << 16; return v.f;
}
__device__ inline unsigned short f2bf(float f) {  // RNE
    union { float f; unsigned int i; } v; v.f = f;
    unsigned int r = v.i + 0x7FFFu + ((v.i >> 16) & 1u);
    return (unsigned short)(r >> 16);
}

// ---------------- degree ----------------
__global__ void k_deg(const int* __restrict__ dst, int ne, int* __restrict__ deg) {
    int e = blockIdx.x * blockDim.x + threadIdx.x;
    if (e < ne) atomicAdd(&deg[dst[e]], 1);
}

// ---------------- scan: per-chunk reduce ----------------
__global__ void k_chunk_reduce(const int* __restrict__ deg, int n, int* __restrict__ bsum) {
    __shared__ int s[256];
    int i = blockIdx.x * 256 + threadIdx.x;
    s[threadIdx.x] = (i < n) ? deg[i] : 0;
    __syncthreads();
    for (int off = 128; off > 0; off >>= 1) {
        if (threadIdx.x < off) s[threadIdx.x] += s[threadIdx.x + off];
        __syncthreads();
    }
    if (threadIdx.x == 0) bsum[blockIdx.x] = s[0];
}

// ---------------- scan of partials: one block (nb <= 512) ----------------
__global__ __launch_bounds__(512) void k_scan_partials(int* __restrict__ bsum, int nb,
                                                       int* __restrict__ rowptr, int n) {
    __shared__ int s[512];
    int tid = threadIdx.x;
    int v = (tid < nb) ? bsum[tid] : 0;
    s[tid] = v;
    __syncthreads();
    for (int off = 1; off < 512; off <<= 1) {
        int t = (tid >= off) ? s[tid - off] : 0;
        __syncthreads();
        s[tid] += t;
        __syncthreads();
    }
    if (tid < nb) bsum[tid] = s[tid] - v;
    if (tid == nb - 1) rowptr[n] = s[tid];
}

// ---------------- per-chunk exclusive scan + invdeg + cursor init ----------------
__global__ void k_chunk_scan(const int* __restrict__ deg, int n, const int* __restrict__ bsum,
                             int* __restrict__ rowptr, int* __restrict__ cursor,
                             float* __restrict__ invd) {
    __shared__ int s[256];
    int tid = threadIdx.x;
    int i = blockIdx.x * 256 + tid;
    int v = (i < n) ? deg[i] : 0;
    s[tid] = v;
    __syncthreads();
    for (int off = 1; off < 256; off <<= 1) {
        int t = (tid >= off) ? s[tid - off] : 0;
        __syncthreads();
        s[tid] += t;
        __syncthreads();
    }
    if (i < n) {
        int excl = bsum[blockIdx.x] + s[tid] - v;
        rowptr[i] = excl;
        cursor[i] = excl;  // k_fill bumps this directly
        invd[i] = 1.0f / fmaxf((float)v, 1.0f);
    }
}

// ---------------- CSR fill (cursor pre-seeded with rowptr) ----------------
__global__ void k_fill(const int* __restrict__ src, const int* __restrict__ dst, int ne,
                       int* __restrict__ cursor, int* __restrict__ col) {
    int e = blockIdx.x * blockDim.x + threadIdx.x;
    if (e < ne) {
        int p = atomicAdd(&cursor[dst[e]], 1);
        col[p] = src[e];
    }
}

// ---------------- prep: h -> HtA bf16, weights -> Btf frag-order, zero deg ----------------
#define T_H   (NN * 32)          // 3,200,000
#define T_BT  (3 * 128 * K2)     // 98,304
#define T_Z   (NN / 4)           // 25,000 int4 stores
__global__ void k_prep(const float* __restrict__ h, const float* __restrict__ Ws,
                       const float* __restrict__ Wn, unsigned short* __restrict__ Ht,
                       unsigned short* __restrict__ Btf, int4* __restrict__ degz) {
    int t = blockIdx.x * 256 + threadIdx.x;
    if (t < T_H) {
        int row = t >> 5, c4 = (t & 31) << 2;
        float4 v = *(const float4*)(h + (size_t)row * D + c4);
        ushort4 o = make_ushort4(f2bf(v.x), f2bf(v.y), f2bf(v.z), f2bf(v.w));
        *(ushort4*)(Ht + (size_t)row * D + c4) = o;
    } else if (t < T_H + T_BT) {
        int t2 = t - T_H;
        int j = t2 & 7; int rest = t2 >> 3;
        int lane = rest & 63; rest >>= 6;
        int ks = rest & 7; rest >>= 3;
        int nf = rest & 7; int l = rest >> 3;
        int nn = nf * 16 + (lane & 15);
        int k = ks * 32 + (lane >> 4) * 8 + j;
        float v = (k < D) ? Ws[(size_t)l * D * D + (size_t)k * D + nn]
                          : Wn[(size_t)l * D * D + (size_t)(k - D) * D + nn];
        Btf[t2] = f2bf(v);
    } else {
        int t3 = t - T_H - T_BT;
        if (t3 < T_Z) degz[t3] = make_int4(0, 0, 0, 0);
    }
}

// ---------------- fused layer, BM=32: gather 32 nodes -> LDS neigh half, h half via
// global_load_lds, MFMA GEMM, LDS-transposed coalesced epilogue.
// launch_bounds(256,4): VGPR cap 128 (no spill); best measured config (round 17).
__global__ __launch_bounds__(256, 4) void k_layer(const unsigned short* __restrict__ Hin,
                                                  const unsigned short* __restrict__ Btf,
                                                  const float* __restrict__ bias,
                                                  const int* __restrict__ rowptr,
                                                  const int* __restrict__ col,
                                                  const float* __restrict__ invd,
                                                  unsigned short* __restrict__ Hout,
                                                  float* __restrict__ outf,
                                                  int relu) {
    __shared__ unsigned short smem[BM * 256];          // 16 KB total
    unsigned short* Ah = smem;                          // 8 KB: h half (256B rows, swizzled)
    unsigned short* An = smem + BM * 128;               // 8 KB: neigh half
    int tid = threadIdx.x;
    int wid = tid >> 6;
    int lane = tid & 63;
    int g = lane >> 4;
    int lane16 = lane & 15;
    int m0 = blockIdx.x * BM;

    // 1) issue h-half staging first: HBM latency hides under the gather.
#pragma unroll
    for (int i = 0; i < 2; ++i) {
        int chunk = wid * 2 + i;
        int o = chunk * 1024 + lane * 16;
        int row = o >> 8;
        int cb = o & 255;
        int scb = cb ^ ((row & 7) << 4);
        const unsigned short* gsrc = Hin + (size_t)(m0 + row) * D + (scb >> 1);
        __builtin_amdgcn_global_load_lds(
            (const __attribute__((address_space(1))) unsigned int*)gsrc,
            (__attribute__((address_space(3))) unsigned int*)((char*)Ah + chunk * 1024),
            16, 0, 0);
    }

    // 2) gather: 2 chunks of 4 parallel nodes per wave (group-local accumulation)
    int coff = lane16 * 8;  // 8 channels (16B) per lane
    for (int c = 0; c < 2; ++c) {
        int row = wid * 8 + c * 4 + g;
        int node = m0 + row;                            // < NN always (NN = 3125*32)
        int e0 = rowptr[node];
        int n = rowptr[node + 1] - e0;
        float inv = invd[node];
        float a0 = 0.f, a1 = 0.f, a2 = 0.f, a3 = 0.f, a4 = 0.f, a5 = 0.f, a6 = 0.f, a7 = 0.f;
        for (int base = 0; base < n; base += 16) {
            int rem = n - base;                         // group-uniform, >= 1
            int lim = rem < 16 ? rem : 16;
            int cidx = lane16 < rem ? lane16 : rem - 1;
            int cv = col[e0 + base + cidx];             // 16 edge ids of this group
            for (int j = 0; j < lim; j += 8) {
                uint4 u[8];
#pragma unroll
                for (int k = 0; k < 8; ++k) {
                    int ee = j + k;
                    int eidx = ee < lim ? ee : lim - 1; // clamp: dup loads cache-hot
                    int si = __shfl(cv, (g << 4) + eidx, 64);
                    u[k] = *(const uint4*)(Hin + (size_t)si * D + coff);
                }
#pragma unroll
                for (int k = 0; k < 8; ++k) {
                    bool live = (j + k) < lim;
                    unsigned int ux = live ? u[k].x : 0u, uy = live ? u[k].y : 0u;
                    unsigned int uz = live ? u[k].z : 0u, uw = live ? u[k].w : 0u;
                    a0 += bflo2f(ux); a1 += bfhi2f(ux);
                    a2 += bflo2f(uy); a3 += bfhi2f(uy);
                    a4 += bflo2f(uz); a5 += bfhi2f(uz);
                    a6 += bflo2f(uw); a7 += bfhi2f(uw);
                }
            }
        }
        uint4 o;
        o.x = ((unsigned int)f2bf(a1 * inv) << 16) | f2bf(a0 * inv);
        o.y = ((unsigned int)f2bf(a3 * inv) << 16) | f2bf(a2 * inv);
        o.z = ((unsigned int)f2bf(a5 * inv) << 16) | f2bf(a4 * inv);
        o.w = ((unsigned int)f2bf(a7 * inv) << 16) | f2bf(a6 * inv);
        int bo = row * 256 + ((lane16 * 16) ^ ((row & 7) << 4));  // same swizzle as Ah
        *(uint4*)((char*)An + bo) = o;
    }

    // 3) B fragments (after gather: keeps gather-phase register pressure low)
    bf16x8 bfr[2][8];
#pragma unroll
    for (int q = 0; q < 2; ++q) {
        int nf = wid + q * 4;
#pragma unroll
        for (int ks = 0; ks < 8; ++ks)
            bfr[q][ks] = *(const bf16x8*)(Btf + (size_t)(((nf * 8 + ks) << 6) + lane) * 8);
    }

    __syncthreads();  // drains global_load_lds + orders ds_writes

    // 4) MFMA: K = 256 = [h: ks 0..3 from Ah | neigh: ks 4..7 from An]
    f32x4 acc[2][2];
#pragma unroll
    for (int mt = 0; mt < 2; ++mt)
#pragma unroll
        for (int q = 0; q < 2; ++q) acc[mt][q] = (f32x4){0.f, 0.f, 0.f, 0.f};

#pragma unroll
    for (int mt = 0; mt < 2; ++mt) {
        int row = mt * 16 + lane16;
        int swz = (row & 7) << 4;
        bf16x8 a[8];
#pragma unroll
        for (int ks = 0; ks < 8; ++ks) {
            int kb = ks * 64 + g * 16;  // byte col in [0,512)
            const char* basep = (kb < 256) ? (const char*)Ah : (const char*)An;
            int cb2 = (kb & 255) ^ swz;
            a[ks] = *(const bf16x8*)(basep + row * 256 + cb2);
        }
#pragma unroll
        for (int ks = 0; ks < 8; ++ks) {
            acc[mt][0] = __builtin_amdgcn_mfma_f32_16x16x32_bf16(a[ks], bfr[0][ks], acc[mt][0], 0, 0, 0);
            acc[mt][1] = __builtin_amdgcn_mfma_f32_16x16x32_bf16(a[ks], bfr[1][ks], acc[mt][1], 0, 0, 0);
        }
    }

    // 5) epilogue: bias+relu -> LDS (swizzled) -> coalesced stores.
    float bv[2];
    bv[0] = bias[wid * 16 + lane16];
    bv[1] = bias[(wid + 4) * 16 + lane16];
    __syncthreads();  // all ds_reads done; smem reusable

    if (outf) {
        // fp32: 32 rows x 512B = 16KB (whole smem)
#pragma unroll
        for (int mt = 0; mt < 2; ++mt) {
#pragma unroll
            for (int q = 0; q < 2; ++q) {
#pragma unroll
                for (int i = 0; i < 4; ++i) {
                    int row = mt * 16 + g * 4 + i;
                    int fe = ((row & 7) << 4) ^ ((row & 8) << 2);
                    float v = acc[mt][q][i] + bv[q];
                    int colb = ((wid + q * 4) * 16 + lane16) * 4;
                    *(float*)((char*)smem + row * 512 + (colb ^ fe)) = v;
                }
            }
        }
        __syncthreads();
        int row = tid >> 3, seg = tid & 7;
        int fe = ((row & 7) << 4) ^ ((row & 8) << 2);
#pragma unroll
        for (int j = 0; j < 4; ++j) {
            int lb = seg * 64 + j * 16;
            uint4 val = *(const uint4*)((char*)smem + row * 512 + (lb ^ fe));
            *(uint4*)((char*)outf + (size_t)(m0 + row) * 512 + lb) = val;
        }
    } else {
        // bf16: 32 rows x 256B = 8KB
#pragma unroll
        for (int mt = 0; mt < 2; ++mt) {
#pragma unroll
            for (int q = 0; q < 2; ++q) {
#pragma unroll
                for (int i = 0; i < 4; ++i) {
                    int row = mt * 16 + g * 4 + i;
                    int fe = ((row & 7) << 4) ^ ((row & 8) << 2);
                    float v = acc[mt][q][i] + bv[q];
                    if (relu) v = fmaxf(v, 0.f);
                    int colb = ((wid + q * 4) * 16 + lane16) * 2;
                    *(unsigned short*)((char*)smem + row * 256 + (colb ^ fe)) = f2bf(v);
                }
            }
        }
        __syncthreads();
        int row = tid >> 3, seg = tid & 7;
        int fe = ((row & 7) << 4) ^ ((row & 8) << 2);
#pragma unroll
        for (int j = 0; j < 2; ++j) {
            int lb = seg * 32 + j * 16;
            uint4 val = *(const uint4*)((char*)smem + row * 256 + (lb ^ fe));
            *(uint4*)((char*)Hout + (size_t)(m0 + row) * 256 + lb) = val;
        }
    }
}

extern "C" void kernel_launch(void* const* d_in, const int* in_sizes, int n_in,
                              void* d_out, int out_size, void* d_ws, size_t ws_size,
                              hipStream_t stream) {
    const float* h = (const float*)d_in[0];
    const int* src = (const int*)d_in[1];
    const int* dst = (const int*)d_in[2];
    const float* Ws = (const float*)d_in[3];
    const float* Wn = (const float*)d_in[4];
    const float* b = (const float*)d_in[5];
    float* out = (float*)d_out;
    int ne = in_sizes[1];

    // workspace
    char* ws = (char*)d_ws;
    unsigned short* HtA = (unsigned short*)ws; ws += (size_t)NN * D * sizeof(unsigned short);
    unsigned short* HtB = (unsigned short*)ws; ws += (size_t)NN * D * sizeof(unsigned short);
    int* col = (int*)ws;    ws += (size_t)ne * sizeof(int);
    unsigned short* Btf = (unsigned short*)ws; ws += (size_t)3 * 128 * K2 * sizeof(unsigned short);
    int* deg = (int*)ws;    ws += (size_t)NN * sizeof(int);
    int* cursor = (int*)ws; ws += (size_t)NN * sizeof(int);
    int* rowptr = (int*)ws; ws += ((size_t)(NN + 1) * sizeof(int) + 15) / 16 * 16;
    int* bsum = (int*)ws;   ws += 512 * sizeof(int);
    float* invd = (float*)ws;

    int nchunk = (NN + 255) / 256;  // 391
    int nprep = (T_H + T_BT + T_Z + 255) / 256;
    k_prep<<<nprep, 256, 0, stream>>>(h, Ws, Wn, HtA, Btf, (int4*)deg);  // also zeros deg
    k_deg<<<(ne + 255) / 256, 256, 0, stream>>>(dst, ne, deg);
    k_chunk_reduce<<<nchunk, 256, 0, stream>>>(deg, NN, bsum);
    k_scan_partials<<<1, 512, 0, stream>>>(bsum, nchunk, rowptr, NN);
    k_chunk_scan<<<nchunk, 256, 0, stream>>>(deg, NN, bsum, rowptr, cursor, invd);
    k_fill<<<(ne + 255) / 256, 256, 0, stream>>>(src, dst, ne, cursor, col);

    int ngrid = NN / BM;  // 3125 exactly
    // layer 0: HtA -> HtB ; layer 1: HtB -> HtA ; layer 2: HtA -> out (fp32)
    k_layer<<<ngrid, 256, 0, stream>>>(HtA, Btf, b, rowptr, col, invd,
                                       HtB, nullptr, 1);
    k_layer<<<ngrid, 256, 0, stream>>>(HtB, Btf + (size_t)1 * 128 * K2, b + 1 * D,
                                       rowptr, col, invd, HtA, nullptr, 1);
    k_layer<<<ngrid, 256, 0, stream>>>(HtA, Btf + (size_t)2 * 128 * K2, b + 2 * D,
                                       rowptr, col, invd, nullptr, out, 0);
}